// Round 2
// baseline (489.879 us; speedup 1.0000x reference)
//
#include <hip/hip_runtime.h>

#define LOG2E 1.4426950408889634f

constexpr int Dn = 128;
constexpr int Nn = 16384;
constexpr int Kn = 64;
constexpr int Bn = 16;

// Prep: one block per k (64 blocks x 64 threads = 1 wave).
// Folds: mu L2-normalize, sigma_inv = exp(-log_sigma), the -2 factor, the
// k-constant (mu_term + log_alpha - 0.5*log_sigma_sum), and log2(e) so the
// main kernel can use exp2. Weight layout: w[k][dh] = float4
// {w1[2dh], w2[2dh], w1[2dh+1], w2[2dh+1]}, all pre-scaled by log2(e).
__global__ __launch_bounds__(64) void gmm_prep(const float* __restrict__ mu,
                                               const float* __restrict__ log_sigma,
                                               const float* __restrict__ log_alpha,
                                               float4* __restrict__ wout,
                                               float* __restrict__ cout) {
    const int k = blockIdx.x;
    const int l = threadIdx.x;
    const int d0 = 2 * l;
    float m0 = mu[k * Dn + d0];
    float m1 = mu[k * Dn + d0 + 1];
    float s0 = log_sigma[k * Dn + d0];
    float s1 = log_sigma[k * Dn + d0 + 1];
    float nrm2 = m0 * m0 + m1 * m1;
    float lss = s0 + s1;
    #pragma unroll
    for (int off = 32; off > 0; off >>= 1) {
        nrm2 += __shfl_xor(nrm2, off);
        lss  += __shfl_xor(lss, off);
    }
    const float inv_nrm = 1.0f / fmaxf(sqrtf(nrm2), 1e-12f);
    const float mn0 = m0 * inv_nrm, mn1 = m1 * inv_nrm;
    const float si0 = expf(-s0), si1 = expf(-s1);
    float mt = mn0 * mn0 * si0 + mn1 * mn1 * si1;
    #pragma unroll
    for (int off = 32; off > 0; off >>= 1) mt += __shfl_xor(mt, off);
    wout[k * (Dn / 2) + l] = make_float4(-si0 * LOG2E, 2.0f * mn0 * si0 * LOG2E,
                                         -si1 * LOG2E, 2.0f * mn1 * si1 * LOG2E);
    if (l == 0) cout[k] = (log_alpha[k] - 0.5f * lss - mt) * LOG2E;
}

__device__ __forceinline__ float2 fma2(float2 a, float2 b, float2 c) {
    return make_float2(fmaf(a.x, b.x, c.x), fmaf(a.y, b.y, c.y));
}

// Main: grid (N/512, B), 256 threads. Each thread owns ALL 64 k's for two
// n's (n0+tid, n0+tid+256). Weight addresses depend only on loop counters ->
// wave-uniform -> scalar (s_load) path; NO LDS in the hot loop at all.
// Softmax is fully thread-local. acc kept as float2 to invite v_pk_fma_f32.
__global__ __launch_bounds__(256, 2) void gmm_main(const float* __restrict__ x,
                                                   const float4* __restrict__ w,
                                                   const float* __restrict__ cks,
                                                   float* __restrict__ out) {
    const int b = blockIdx.y;
    const int n0 = blockIdx.x * 512;
    const int lane = threadIdx.x;   // n = n0 + lane, n0 + lane + 256

    const float* xp = x + (size_t)b * Dn * Nn + n0 + lane;

    float2 acc[Kn];
    #pragma unroll
    for (int k = 0; k < Kn; ++k) acc[k] = make_float2(0.0f, 0.0f);

    for (int dh = 0; dh < Dn / 2; ++dh) {
        const float2 x0 = make_float2(xp[0], xp[256]);        // d = 2*dh
        const float2 x1 = make_float2(xp[Nn], xp[Nn + 256]);  // d = 2*dh+1
        xp += 2 * Nn;
        const float4* wk = w + dh;
        #pragma unroll
        for (int k = 0; k < Kn; ++k) {
            const float4 wv = wk[k * (Dn / 2)];   // uniform address -> s_load
            const float2 t0 = fma2(x0, make_float2(wv.x, wv.x),
                                       make_float2(wv.y, wv.y));
            acc[k] = fma2(x0, t0, acc[k]);
            const float2 t1 = fma2(x1, make_float2(wv.z, wv.z),
                                       make_float2(wv.w, wv.w));
            acc[k] = fma2(x1, t1, acc[k]);
        }
    }

    // ---- thread-local softmax (log2 domain) ----
    float m0 = -3.0e38f, m1 = -3.0e38f;
    #pragma unroll
    for (int k = 0; k < Kn; ++k) {
        const float c = cks[k];                  // uniform -> s_load
        acc[k].x += c;
        acc[k].y += c;
        m0 = fmaxf(m0, acc[k].x);
        m1 = fmaxf(m1, acc[k].y);
    }
    float s0 = 0.0f, s1 = 0.0f;
    #pragma unroll
    for (int k = 0; k < Kn; ++k) {
        acc[k].x = __builtin_amdgcn_exp2f(acc[k].x - m0);
        acc[k].y = __builtin_amdgcn_exp2f(acc[k].y - m1);
        s0 += acc[k].x;
        s1 += acc[k].y;
    }
    const float r0 = 1.0f / s0;
    const float r1 = 1.0f / s1;

    float* op = out + (size_t)b * Kn * Nn + n0 + lane;
    #pragma unroll
    for (int k = 0; k < Kn; ++k) {
        op[k * Nn] = acc[k].x * r0;
        op[k * Nn + 256] = acc[k].y * r1;
    }
}

extern "C" void kernel_launch(void* const* d_in, const int* in_sizes, int n_in,
                              void* d_out, int out_size, void* d_ws, size_t ws_size,
                              hipStream_t stream) {
    const float* x  = (const float*)d_in[0];
    const float* mu = (const float*)d_in[1];
    const float* ls = (const float*)d_in[2];
    const float* la = (const float*)d_in[3];
    float* out = (float*)d_out;

    float4* wbuf = (float4*)d_ws;
    float*  cbuf = (float*)((char*)d_ws + (size_t)Kn * (Dn / 2) * sizeof(float4));

    gmm_prep<<<dim3(Kn), dim3(64), 0, stream>>>(mu, ls, la, wbuf, cbuf);
    gmm_main<<<dim3(Nn / 512, Bn), dim3(256), 0, stream>>>(x, wbuf, cbuf, out);
}

// Round 3
// 292.635 us; speedup vs baseline: 1.6740x; 1.6740x over previous
//
#include <hip/hip_runtime.h>

#define LOG2E 1.4426950408889634f

constexpr int Dn = 128;
constexpr int Nn = 16384;
constexpr int Kn = 64;
constexpr int Bn = 16;

// Prep: folds mu-normalize, exp(-log_sigma), factor -2, k-constant and log2e.
// Weight layout: w[k*64+dh] = {w1[2dh], w2[2dh], w1[2dh+1], w2[2dh+1]} * log2e.
__global__ __launch_bounds__(64) void gmm_prep(const float* __restrict__ mu,
                                               const float* __restrict__ log_sigma,
                                               const float* __restrict__ log_alpha,
                                               float4* __restrict__ wout,
                                               float* __restrict__ cout) {
    const int k = blockIdx.x;
    const int l = threadIdx.x;
    const int d0 = 2 * l;
    float m0 = mu[k * Dn + d0];
    float m1 = mu[k * Dn + d0 + 1];
    float s0 = log_sigma[k * Dn + d0];
    float s1 = log_sigma[k * Dn + d0 + 1];
    float nrm2 = m0 * m0 + m1 * m1;
    float lss = s0 + s1;
    #pragma unroll
    for (int off = 32; off > 0; off >>= 1) {
        nrm2 += __shfl_xor(nrm2, off);
        lss  += __shfl_xor(lss, off);
    }
    const float inv_nrm = 1.0f / fmaxf(sqrtf(nrm2), 1e-12f);
    const float mn0 = m0 * inv_nrm, mn1 = m1 * inv_nrm;
    const float si0 = expf(-s0), si1 = expf(-s1);
    float mt = mn0 * mn0 * si0 + mn1 * mn1 * si1;
    #pragma unroll
    for (int off = 32; off > 0; off >>= 1) mt += __shfl_xor(mt, off);
    wout[k * (Dn / 2) + l] = make_float4(-si0 * LOG2E, 2.0f * mn0 * si0 * LOG2E,
                                         -si1 * LOG2E, 2.0f * mn1 * si1 * LOG2E);
    if (l == 0) cout[k] = (log_alpha[k] - 0.5f * lss - mt) * LOG2E;
}

__device__ __forceinline__ float4 fmax4(float4 a, float4 b) {
    return make_float4(fmaxf(a.x, b.x), fmaxf(a.y, b.y),
                       fmaxf(a.z, b.z), fmaxf(a.w, b.w));
}
__device__ __forceinline__ float4 add4(float4 a, float4 b) {
    return make_float4(a.x + b.x, a.y + b.y, a.z + b.z, a.w + b.w);
}

// Main: 512 threads = 8 waves. Wave g owns k in [8g,8g+8); lane owns 8
// consecutive n's. 32 FMA per ds_read_b128 (broadcast) -> LDS pipe (41us)
// below VALU floor (55us). acc=64 VGPRs; launch_bounds(512,4) caps at 128.
// Grid = 512 blocks = exactly 2 blocks/CU (LDS 80KB/block).
__global__ __launch_bounds__(512, 4) void gmm_main(const float* __restrict__ x,
                                                   const float4* __restrict__ w,
                                                   const float* __restrict__ cks,
                                                   float* __restrict__ out) {
    __shared__ float4 sW[Kn * (Dn / 2)];   // 64 KB: sW[k*64 + dh]
    __shared__ float  sRed[8][512];        // 16 KB cross-wave softmax buffer

    const int tid = threadIdx.x;
    #pragma unroll
    for (int i = 0; i < 8; ++i) sW[tid + i * 512] = w[tid + i * 512];

    const int g = tid >> 6;            // k-group == wave index
    const int l = tid & 63;
    const int b = blockIdx.y;
    const int nloc = 8 * l;            // local n within the 512 window
    const size_t nbase = (size_t)blockIdx.x * 512 + nloc;

    float acc[8][8];
    #pragma unroll
    for (int k = 0; k < 8; ++k)
        #pragma unroll
        for (int j = 0; j < 8; ++j) acc[k][j] = 0.0f;

    const float* xp = x + (size_t)b * Dn * Nn + nbase;
    __syncthreads();

    for (int dh = 0; dh < Dn / 2; ++dh) {
        const float4 xa0 = *(const float4*)(xp);           // d=2dh,   n+0..3
        const float4 xa1 = *(const float4*)(xp + 4);       // d=2dh,   n+4..7
        const float4 xb0 = *(const float4*)(xp + Nn);      // d=2dh+1, n+0..3
        const float4 xb1 = *(const float4*)(xp + Nn + 4);  // d=2dh+1, n+4..7
        xp += 2 * Nn;
        const float4* wp = &sW[g * 8 * (Dn / 2) + dh];
        #pragma unroll
        for (int k = 0; k < 8; ++k) {
            const float4 wv = wp[k * (Dn / 2)];  // wave-uniform -> broadcast
            acc[k][0] = fmaf(xa0.x, fmaf(xa0.x, wv.x, wv.y), acc[k][0]);
            acc[k][1] = fmaf(xa0.y, fmaf(xa0.y, wv.x, wv.y), acc[k][1]);
            acc[k][2] = fmaf(xa0.z, fmaf(xa0.z, wv.x, wv.y), acc[k][2]);
            acc[k][3] = fmaf(xa0.w, fmaf(xa0.w, wv.x, wv.y), acc[k][3]);
            acc[k][4] = fmaf(xa1.x, fmaf(xa1.x, wv.x, wv.y), acc[k][4]);
            acc[k][5] = fmaf(xa1.y, fmaf(xa1.y, wv.x, wv.y), acc[k][5]);
            acc[k][6] = fmaf(xa1.z, fmaf(xa1.z, wv.x, wv.y), acc[k][6]);
            acc[k][7] = fmaf(xa1.w, fmaf(xa1.w, wv.x, wv.y), acc[k][7]);
            acc[k][0] = fmaf(xb0.x, fmaf(xb0.x, wv.z, wv.w), acc[k][0]);
            acc[k][1] = fmaf(xb0.y, fmaf(xb0.y, wv.z, wv.w), acc[k][1]);
            acc[k][2] = fmaf(xb0.z, fmaf(xb0.z, wv.z, wv.w), acc[k][2]);
            acc[k][3] = fmaf(xb0.w, fmaf(xb0.w, wv.z, wv.w), acc[k][3]);
            acc[k][4] = fmaf(xb1.x, fmaf(xb1.x, wv.z, wv.w), acc[k][4]);
            acc[k][5] = fmaf(xb1.y, fmaf(xb1.y, wv.z, wv.w), acc[k][5]);
            acc[k][6] = fmaf(xb1.z, fmaf(xb1.z, wv.z, wv.w), acc[k][6]);
            acc[k][7] = fmaf(xb1.w, fmaf(xb1.w, wv.z, wv.w), acc[k][7]);
        }
    }

    // per-k constants (wave-uniform -> s_load)
    #pragma unroll
    for (int k = 0; k < 8; ++k) {
        const float c = cks[g * 8 + k];
        #pragma unroll
        for (int j = 0; j < 8; ++j) acc[k][j] += c;
    }

    // ---- softmax: cross-wave max ----
    float4 m0 = make_float4(acc[0][0], acc[0][1], acc[0][2], acc[0][3]);
    float4 m1 = make_float4(acc[0][4], acc[0][5], acc[0][6], acc[0][7]);
    #pragma unroll
    for (int k = 1; k < 8; ++k) {
        m0 = fmax4(m0, make_float4(acc[k][0], acc[k][1], acc[k][2], acc[k][3]));
        m1 = fmax4(m1, make_float4(acc[k][4], acc[k][5], acc[k][6], acc[k][7]));
    }
    *(float4*)&sRed[g][nloc]     = m0;
    *(float4*)&sRed[g][nloc + 4] = m1;
    __syncthreads();
    #pragma unroll
    for (int gg = 0; gg < 8; ++gg) {
        m0 = fmax4(m0, *(const float4*)&sRed[gg][nloc]);
        m1 = fmax4(m1, *(const float4*)&sRed[gg][nloc + 4]);
    }
    __syncthreads();   // before reusing sRed for sums

    // ---- exp2 + cross-wave sum ----
    float4 s0 = make_float4(0.f, 0.f, 0.f, 0.f);
    float4 s1 = make_float4(0.f, 0.f, 0.f, 0.f);
    #pragma unroll
    for (int k = 0; k < 8; ++k) {
        acc[k][0] = __builtin_amdgcn_exp2f(acc[k][0] - m0.x); s0.x += acc[k][0];
        acc[k][1] = __builtin_amdgcn_exp2f(acc[k][1] - m0.y); s0.y += acc[k][1];
        acc[k][2] = __builtin_amdgcn_exp2f(acc[k][2] - m0.z); s0.z += acc[k][2];
        acc[k][3] = __builtin_amdgcn_exp2f(acc[k][3] - m0.w); s0.w += acc[k][3];
        acc[k][4] = __builtin_amdgcn_exp2f(acc[k][4] - m1.x); s1.x += acc[k][4];
        acc[k][5] = __builtin_amdgcn_exp2f(acc[k][5] - m1.y); s1.y += acc[k][5];
        acc[k][6] = __builtin_amdgcn_exp2f(acc[k][6] - m1.z); s1.z += acc[k][6];
        acc[k][7] = __builtin_amdgcn_exp2f(acc[k][7] - m1.w); s1.w += acc[k][7];
    }
    *(float4*)&sRed[g][nloc]     = s0;
    *(float4*)&sRed[g][nloc + 4] = s1;
    __syncthreads();
    s0 = make_float4(0.f, 0.f, 0.f, 0.f);
    s1 = make_float4(0.f, 0.f, 0.f, 0.f);
    #pragma unroll
    for (int gg = 0; gg < 8; ++gg) {
        s0 = add4(s0, *(const float4*)&sRed[gg][nloc]);
        s1 = add4(s1, *(const float4*)&sRed[gg][nloc + 4]);
    }
    const float4 r0 = make_float4(1.0f / s0.x, 1.0f / s0.y, 1.0f / s0.z, 1.0f / s0.w);
    const float4 r1 = make_float4(1.0f / s1.x, 1.0f / s1.y, 1.0f / s1.z, 1.0f / s1.w);

    // ---- store: out[b][k][n], 2x float4 per k, coalesced ----
    float* op = out + (size_t)(b * Kn + g * 8) * Nn + nbase;
    #pragma unroll
    for (int k = 0; k < 8; ++k) {
        *(float4*)(op)     = make_float4(acc[k][0] * r0.x, acc[k][1] * r0.y,
                                         acc[k][2] * r0.z, acc[k][3] * r0.w);
        *(float4*)(op + 4) = make_float4(acc[k][4] * r1.x, acc[k][5] * r1.y,
                                         acc[k][6] * r1.z, acc[k][7] * r1.w);
        op += Nn;
    }
}

extern "C" void kernel_launch(void* const* d_in, const int* in_sizes, int n_in,
                              void* d_out, int out_size, void* d_ws, size_t ws_size,
                              hipStream_t stream) {
    const float* x  = (const float*)d_in[0];
    const float* mu = (const float*)d_in[1];
    const float* ls = (const float*)d_in[2];
    const float* la = (const float*)d_in[3];
    float* out = (float*)d_out;

    float4* wbuf = (float4*)d_ws;
    float*  cbuf = (float*)((char*)d_ws + (size_t)Kn * (Dn / 2) * sizeof(float4));

    gmm_prep<<<dim3(Kn), dim3(64), 0, stream>>>(mu, ls, la, wbuf, cbuf);
    gmm_main<<<dim3(Nn / 512, Bn), dim3(512), 0, stream>>>(x, wbuf, cbuf, out);
}

// Round 4
// 287.967 us; speedup vs baseline: 1.7012x; 1.0162x over previous
//
#include <hip/hip_runtime.h>

#define LOG2E 1.4426950408889634f

constexpr int Dn = 128;
constexpr int Nn = 16384;
constexpr int Kn = 64;
constexpr int Bn = 16;

// Prep: folds mu-normalize, exp(-log_sigma), factor -2, k-constant and log2e.
// Weight layout: w[k*64+dh] = {w1[2dh], w2[2dh], w1[2dh+1], w2[2dh+1]} * log2e.
__global__ __launch_bounds__(64) void gmm_prep(const float* __restrict__ mu,
                                               const float* __restrict__ log_sigma,
                                               const float* __restrict__ log_alpha,
                                               float4* __restrict__ wout,
                                               float* __restrict__ cout) {
    const int k = blockIdx.x;
    const int l = threadIdx.x;
    const int d0 = 2 * l;
    float m0 = mu[k * Dn + d0];
    float m1 = mu[k * Dn + d0 + 1];
    float s0 = log_sigma[k * Dn + d0];
    float s1 = log_sigma[k * Dn + d0 + 1];
    float nrm2 = m0 * m0 + m1 * m1;
    float lss = s0 + s1;
    #pragma unroll
    for (int off = 32; off > 0; off >>= 1) {
        nrm2 += __shfl_xor(nrm2, off);
        lss  += __shfl_xor(lss, off);
    }
    const float inv_nrm = 1.0f / fmaxf(sqrtf(nrm2), 1e-12f);
    const float mn0 = m0 * inv_nrm, mn1 = m1 * inv_nrm;
    const float si0 = expf(-s0), si1 = expf(-s1);
    float mt = mn0 * mn0 * si0 + mn1 * mn1 * si1;
    #pragma unroll
    for (int off = 32; off > 0; off >>= 1) mt += __shfl_xor(mt, off);
    wout[k * (Dn / 2) + l] = make_float4(-si0 * LOG2E, 2.0f * mn0 * si0 * LOG2E,
                                         -si1 * LOG2E, 2.0f * mn1 * si1 * LOG2E);
    if (l == 0) cout[k] = (log_alpha[k] - 0.5f * lss - mt) * LOG2E;
}

__device__ __forceinline__ float4 fmax4(float4 a, float4 b) {
    return make_float4(fmaxf(a.x, b.x), fmaxf(a.y, b.y),
                       fmaxf(a.z, b.z), fmaxf(a.w, b.w));
}
__device__ __forceinline__ float4 add4(float4 a, float4 b) {
    return make_float4(a.x + b.x, a.y + b.y, a.z + b.z, a.w + b.w);
}

// Main: 512 threads = 8 waves. Wave g owns k in [8g,8g+8); lane owns 8
// consecutive n's. 32 FMA per broadcast ds_read_b128 -> LDS pipe ~75% of the
// 55us VALU floor. LDS 80KB -> exactly 2 blocks/CU = 4 waves/EU.
// amdgpu_waves_per_eu(4,4): pin the allocator to the 128-VGPR budget so the
// ~90-reg live set (64 acc + 16 x + addrs) stays in arch VGPRs — round 3's
// launch_bounds(512,4) let it squeeze to 64 VGPRs + AGPR/scratch shuffling
// (VGPR_Count=64, +16MB scratch writes, VALU 1.3x inflated).
__global__ __launch_bounds__(512)
__attribute__((amdgpu_waves_per_eu(4, 4)))
void gmm_main(const float* __restrict__ x,
              const float4* __restrict__ w,
              const float* __restrict__ cks,
              float* __restrict__ out) {
    __shared__ float4 sW[Kn * (Dn / 2)];   // 64 KB: sW[k*64 + dh]
    __shared__ float  sRed[8][512];        // 16 KB cross-wave softmax buffer

    const int tid = threadIdx.x;
    #pragma unroll
    for (int i = 0; i < 8; ++i) sW[tid + i * 512] = w[tid + i * 512];

    const int g = tid >> 6;            // k-group == wave index
    const int l = tid & 63;
    const int b = blockIdx.y;
    const int nloc = 8 * l;            // local n within the 512 window
    const size_t nbase = (size_t)blockIdx.x * 512 + nloc;

    // init acc with the per-k constant (folds the epilogue add)
    float acc[8][8];
    #pragma unroll
    for (int k = 0; k < 8; ++k) {
        const float c = cks[g * 8 + k];   // wave-uniform -> s_load
        #pragma unroll
        for (int j = 0; j < 8; ++j) acc[k][j] = c;
    }

    const float* xp = x + (size_t)b * Dn * Nn + nbase;
    __syncthreads();

    for (int dh = 0; dh < Dn / 2; ++dh) {
        const float4 xa0 = *(const float4*)(xp);           // d=2dh,   n+0..3
        const float4 xa1 = *(const float4*)(xp + 4);       // d=2dh,   n+4..7
        const float4 xb0 = *(const float4*)(xp + Nn);      // d=2dh+1, n+0..3
        const float4 xb1 = *(const float4*)(xp + Nn + 4);  // d=2dh+1, n+4..7
        xp += 2 * Nn;
        const float4* wp = &sW[g * 8 * (Dn / 2) + dh];
        #pragma unroll
        for (int k = 0; k < 8; ++k) {
            const float4 wv = wp[k * (Dn / 2)];  // wave-uniform -> broadcast
            acc[k][0] = fmaf(xa0.x, fmaf(xa0.x, wv.x, wv.y), acc[k][0]);
            acc[k][1] = fmaf(xa0.y, fmaf(xa0.y, wv.x, wv.y), acc[k][1]);
            acc[k][2] = fmaf(xa0.z, fmaf(xa0.z, wv.x, wv.y), acc[k][2]);
            acc[k][3] = fmaf(xa0.w, fmaf(xa0.w, wv.x, wv.y), acc[k][3]);
            acc[k][4] = fmaf(xa1.x, fmaf(xa1.x, wv.x, wv.y), acc[k][4]);
            acc[k][5] = fmaf(xa1.y, fmaf(xa1.y, wv.x, wv.y), acc[k][5]);
            acc[k][6] = fmaf(xa1.z, fmaf(xa1.z, wv.x, wv.y), acc[k][6]);
            acc[k][7] = fmaf(xa1.w, fmaf(xa1.w, wv.x, wv.y), acc[k][7]);
            acc[k][0] = fmaf(xb0.x, fmaf(xb0.x, wv.z, wv.w), acc[k][0]);
            acc[k][1] = fmaf(xb0.y, fmaf(xb0.y, wv.z, wv.w), acc[k][1]);
            acc[k][2] = fmaf(xb0.z, fmaf(xb0.z, wv.z, wv.w), acc[k][2]);
            acc[k][3] = fmaf(xb0.w, fmaf(xb0.w, wv.z, wv.w), acc[k][3]);
            acc[k][4] = fmaf(xb1.x, fmaf(xb1.x, wv.z, wv.w), acc[k][4]);
            acc[k][5] = fmaf(xb1.y, fmaf(xb1.y, wv.z, wv.w), acc[k][5]);
            acc[k][6] = fmaf(xb1.z, fmaf(xb1.z, wv.z, wv.w), acc[k][6]);
            acc[k][7] = fmaf(xb1.w, fmaf(xb1.w, wv.z, wv.w), acc[k][7]);
        }
    }

    // ---- softmax: cross-wave max ----
    float4 m0 = make_float4(acc[0][0], acc[0][1], acc[0][2], acc[0][3]);
    float4 m1 = make_float4(acc[0][4], acc[0][5], acc[0][6], acc[0][7]);
    #pragma unroll
    for (int k = 1; k < 8; ++k) {
        m0 = fmax4(m0, make_float4(acc[k][0], acc[k][1], acc[k][2], acc[k][3]));
        m1 = fmax4(m1, make_float4(acc[k][4], acc[k][5], acc[k][6], acc[k][7]));
    }
    *(float4*)&sRed[g][nloc]     = m0;
    *(float4*)&sRed[g][nloc + 4] = m1;
    __syncthreads();
    #pragma unroll
    for (int gg = 0; gg < 8; ++gg) {
        m0 = fmax4(m0, *(const float4*)&sRed[gg][nloc]);
        m1 = fmax4(m1, *(const float4*)&sRed[gg][nloc + 4]);
    }
    __syncthreads();   // before reusing sRed for sums

    // ---- exp2 + cross-wave sum ----
    float4 s0 = make_float4(0.f, 0.f, 0.f, 0.f);
    float4 s1 = make_float4(0.f, 0.f, 0.f, 0.f);
    #pragma unroll
    for (int k = 0; k < 8; ++k) {
        acc[k][0] = __builtin_amdgcn_exp2f(acc[k][0] - m0.x); s0.x += acc[k][0];
        acc[k][1] = __builtin_amdgcn_exp2f(acc[k][1] - m0.y); s0.y += acc[k][1];
        acc[k][2] = __builtin_amdgcn_exp2f(acc[k][2] - m0.z); s0.z += acc[k][2];
        acc[k][3] = __builtin_amdgcn_exp2f(acc[k][3] - m0.w); s0.w += acc[k][3];
        acc[k][4] = __builtin_amdgcn_exp2f(acc[k][4] - m1.x); s1.x += acc[k][4];
        acc[k][5] = __builtin_amdgcn_exp2f(acc[k][5] - m1.y); s1.y += acc[k][5];
        acc[k][6] = __builtin_amdgcn_exp2f(acc[k][6] - m1.z); s1.z += acc[k][6];
        acc[k][7] = __builtin_amdgcn_exp2f(acc[k][7] - m1.w); s1.w += acc[k][7];
    }
    *(float4*)&sRed[g][nloc]     = s0;
    *(float4*)&sRed[g][nloc + 4] = s1;
    __syncthreads();
    s0 = make_float4(0.f, 0.f, 0.f, 0.f);
    s1 = make_float4(0.f, 0.f, 0.f, 0.f);
    #pragma unroll
    for (int gg = 0; gg < 8; ++gg) {
        s0 = add4(s0, *(const float4*)&sRed[gg][nloc]);
        s1 = add4(s1, *(const float4*)&sRed[gg][nloc + 4]);
    }
    const float4 r0 = make_float4(1.0f / s0.x, 1.0f / s0.y, 1.0f / s0.z, 1.0f / s0.w);
    const float4 r1 = make_float4(1.0f / s1.x, 1.0f / s1.y, 1.0f / s1.z, 1.0f / s1.w);

    // ---- store: out[b][k][n], 2x float4 per k, coalesced ----
    float* op = out + (size_t)(b * Kn + g * 8) * Nn + nbase;
    #pragma unroll
    for (int k = 0; k < 8; ++k) {
        *(float4*)(op)     = make_float4(acc[k][0] * r0.x, acc[k][1] * r0.y,
                                         acc[k][2] * r0.z, acc[k][3] * r0.w);
        *(float4*)(op + 4) = make_float4(acc[k][4] * r1.x, acc[k][5] * r1.y,
                                         acc[k][6] * r1.z, acc[k][7] * r1.w);
        op += Nn;
    }
}

extern "C" void kernel_launch(void* const* d_in, const int* in_sizes, int n_in,
                              void* d_out, int out_size, void* d_ws, size_t ws_size,
                              hipStream_t stream) {
    const float* x  = (const float*)d_in[0];
    const float* mu = (const float*)d_in[1];
    const float* ls = (const float*)d_in[2];
    const float* la = (const float*)d_in[3];
    float* out = (float*)d_out;

    float4* wbuf = (float4*)d_ws;
    float*  cbuf = (float*)((char*)d_ws + (size_t)Kn * (Dn / 2) * sizeof(float4));

    gmm_prep<<<dim3(Kn), dim3(64), 0, stream>>>(mu, ls, la, wbuf, cbuf);
    gmm_main<<<dim3(Nn / 512, Bn), dim3(512), 0, stream>>>(x, wbuf, cbuf, out);
}